// Round 1
// baseline (344.689 us; speedup 1.0000x reference)
//
#include <hip/hip_runtime.h>
#include <math.h>

#define N2C 16000
#define N1C 4000
#define N0C 1000
#define DEG 32
#define CH 256      // H*O
#define NHEAD 4
#define ODIM 64
#define ALPHA 0.2f

// ---------------- repack: Wc0[k][h*64+o]=W0[h][k][o]; same W1; linT[k][j]=linW[j][k]
__global__ __launch_bounds__(256) void repack_kernel(
    const float* __restrict__ W0, const float* __restrict__ W1,
    const float* __restrict__ linW,
    float* __restrict__ Wc0, float* __restrict__ Wc1, float* __restrict__ linT)
{
    int g = blockIdx.x * 256 + threadIdx.x;   // 0 .. 3*65536-1
    int which = g >> 16;
    int idx = g & 65535;
    int k = idx >> 8, c = idx & 255;
    if (which == 0) {
        int hd = c >> 6, o = c & 63;
        Wc0[idx] = W0[hd * (256 * 64) + k * 64 + o];
    } else if (which == 1) {
        int hd = c >> 6, o = c & 63;
        Wc1[idx] = W1[hd * (256 * 64) + k * 64 + o];
    } else {
        linT[idx] = linW[c * 256 + k];
    }
}

// ---------------- fp32 GEMM: out[M x 256] = A[M x 256] * W[256 x 256] (+bias,tanh)
// 256 threads: thread = (rg = t>>6 row-group, cg = t&63 -> cols 4cg..4cg+3)
template<int EPI, int ROWS>
__global__ __launch_bounds__(256) void gemm_kernel(
    const float* __restrict__ A, const float* __restrict__ W,
    const float* __restrict__ bias, float* __restrict__ out, int M)
{
    __shared__ float4 xs4[ROWS][64];
    const int t = threadIdx.x;
    const int row0 = blockIdx.x * ROWS;
    for (int i = t; i < ROWS * 64; i += 256) {
        int r = i >> 6, c4 = i & 63;
        int gr = row0 + r; if (gr > M - 1) gr = M - 1;   // clamp (reads stay in-bounds)
        xs4[r][c4] = ((const float4*)A)[gr * 64 + c4];
    }
    __syncthreads();
    const int cg = t & 63;
    const int rg = t >> 6;
    constexpr int RPT = ROWS / 4;
    float4 acc[RPT];
#pragma unroll
    for (int i = 0; i < RPT; ++i) acc[i] = make_float4(0.f, 0.f, 0.f, 0.f);
    const float4* W4 = (const float4*)W;
    for (int k4 = 0; k4 < 64; ++k4) {
        float4 w0 = W4[(k4 * 4 + 0) * 64 + cg];
        float4 w1 = W4[(k4 * 4 + 1) * 64 + cg];
        float4 w2 = W4[(k4 * 4 + 2) * 64 + cg];
        float4 w3 = W4[(k4 * 4 + 3) * 64 + cg];
#pragma unroll
        for (int i = 0; i < RPT; ++i) {
            float4 xv = xs4[rg * RPT + i][k4];   // wave-uniform address -> LDS broadcast
            acc[i].x += xv.x * w0.x + xv.y * w1.x + xv.z * w2.x + xv.w * w3.x;
            acc[i].y += xv.x * w0.y + xv.y * w1.y + xv.z * w2.y + xv.w * w3.y;
            acc[i].z += xv.x * w0.z + xv.y * w1.z + xv.z * w2.z + xv.w * w3.z;
            acc[i].w += xv.x * w0.w + xv.y * w1.w + xv.z * w2.w + xv.w * w3.w;
        }
    }
#pragma unroll
    for (int i = 0; i < RPT; ++i) {
        int gr = row0 + rg * RPT + i;
        if (gr >= M) continue;
        float4 v = acc[i];
        if (EPI == 1) {
            float4 b = ((const float4*)bias)[cg];
            v.x = tanhf(v.x + b.x); v.y = tanhf(v.y + b.y);
            v.z = tanhf(v.z + b.z); v.w = tanhf(v.w + b.w);
        }
        ((float4*)out)[gr * 64 + cg] = v;
    }
}

// ---------------- per-node attention scores: s_t[h][n]=dot(h0[n,h*64:],a[h,:64]) etc.
__global__ __launch_bounds__(64) void scores_kernel(
    const float* __restrict__ h, const float* __restrict__ a,
    float* __restrict__ s_t, float* __restrict__ s_n, int N)
{
    const int n = blockIdx.x;
    const int lane = threadIdx.x;
#pragma unroll
    for (int hd = 0; hd < NHEAD; ++hd) {
        float v = h[n * CH + hd * ODIM + lane];
        float pt = v * a[hd * 2 * ODIM + lane];
        float pn = v * a[hd * 2 * ODIM + ODIM + lane];
#pragma unroll
        for (int off = 32; off > 0; off >>= 1) {
            pt += __shfl_down(pt, off);
            pn += __shfl_down(pn, off);
        }
        if (lane == 0) { s_t[hd * N + n] = pt; s_n[hd * N + n] = pn; }
    }
}

// ---------------- per-target: dedupe, edge-softmax, aggregate, ELU
__global__ __launch_bounds__(256) void att_kernel(
    const float* __restrict__ hprev, const int* __restrict__ nbr_arr,
    const float* __restrict__ s_t, const float* __restrict__ s_n,
    float* __restrict__ xnext, int T, int Nsrc)
{
    __shared__ int nbr[DEG + 1];
    __shared__ int keep[DEG + 1];
    __shared__ float ev[NHEAD][DEG + 1];
    __shared__ float att[NHEAD][DEG + 1];
    const int tgt = blockIdx.x;
    const int t = threadIdx.x;
    if (t < DEG) nbr[t] = nbr_arr[tgt * DEG + t];
    else if (t == DEG) nbr[DEG] = nbr_arr[T * DEG + tgt];  // self-loop
    __syncthreads();
    if (t < DEG + 1) {
        int me = nbr[t]; int k = 1;
        for (int j = 0; j < t; ++j) if (nbr[j] == me) { k = 0; break; }
        keep[t] = k;
    }
    if (t < NHEAD * (DEG + 1)) {
        int hd = t / (DEG + 1), i = t % (DEG + 1);
        float e = s_t[hd * Nsrc + tgt] + s_n[hd * Nsrc + nbr[i]];
        ev[hd][i] = (e >= 0.f) ? e : ALPHA * e;   // LeakyReLU(0.2)
    }
    __syncthreads();
    if (t < NHEAD) {
        float m = -1e30f;
        for (int i = 0; i <= DEG; ++i) if (keep[i]) m = fmaxf(m, ev[t][i]);
        float Z = 0.f;
        for (int i = 0; i <= DEG; ++i) {
            float w = keep[i] ? expf(ev[t][i] - m) : 0.f;
            Z += w; att[t][i] = w;
        }
        float rz = 1.f / Z;
        for (int i = 0; i <= DEG; ++i) att[t][i] *= rz;
    }
    __syncthreads();
    const int hd = t >> 6;
    float acc = 0.f;
    for (int i = 0; i <= DEG; ++i) {
        float w = att[hd][i];                    // wave-uniform
        if (w > 0.f) acc += w * hprev[nbr[i] * CH + t];
    }
    xnext[tgt * CH + t] = (acc > 0.f) ? acc : expm1f(acc);   // ELU
}

extern "C" void kernel_launch(void* const* d_in, const int* in_sizes, int n_in,
                              void* d_out, int out_size, void* d_ws, size_t ws_size,
                              hipStream_t stream)
{
    const float* x    = (const float*)d_in[0];
    const float* W0   = (const float*)d_in[1];
    const float* a0   = (const float*)d_in[2];
    const float* W1   = (const float*)d_in[3];
    const float* a1   = (const float*)d_in[4];
    const float* linW = (const float*)d_in[5];
    const float* linb = (const float*)d_in[6];
    const int* adj1_nbr = (const int*)d_in[8];
    const int* adj0_nbr = (const int*)d_in[10];

    float* ws  = (float*)d_ws;
    float* Wc0 = ws;                      // 65536
    float* Wc1 = ws + 65536;              // 65536
    float* linT = ws + 131072;            // 65536
    float* h0  = ws + 196608;             // 16000*256 = 4096000 (reused as h1)
    float* s0t = h0 + 4096000;            // 64000 (reused as s1t)
    float* s0n = s0t + 64000;             // 64000 (reused as s1n)
    float* x1  = s0n + 64000;             // 4000*256 (+margin)
    float* x2  = x1 + 1024000 + 8192;     // 1000*256 (+margin)

    repack_kernel<<<768, 256, 0, stream>>>(W0, W1, linW, Wc0, Wc1, linT);

    // layer 1
    gemm_kernel<0, 32><<<N2C / 32, 256, 0, stream>>>(x, Wc0, nullptr, h0, N2C);
    scores_kernel<<<N2C, 64, 0, stream>>>(h0, a0, s0t, s0n, N2C);
    att_kernel<<<N1C, 256, 0, stream>>>(h0, adj1_nbr, s0t, s0n, x1, N1C, N2C);

    // layer 2 (h1 aliases h0 region; s1 alias s0)
    gemm_kernel<0, 32><<<N1C / 32, 256, 0, stream>>>(x1, Wc1, nullptr, h0, N1C);
    scores_kernel<<<N1C, 64, 0, stream>>>(h0, a1, s0t, s0n, N1C);
    att_kernel<<<N0C, 256, 0, stream>>>(h0, adj0_nbr, s0t, s0n, x2, N0C, N1C);

    // final Linear + Tanh
    gemm_kernel<1, 8><<<N0C / 8, 256, 0, stream>>>(x2, linT, linb, (float*)d_out, N0C);
}

// Round 2
// 242.419 us; speedup vs baseline: 1.4219x; 1.4219x over previous
//
#include <hip/hip_runtime.h>
#include <math.h>

#define N2C 16000
#define N1C 4000
#define N0C 1000
#define DEG 32
#define CH 256      // H*O
#define NHEAD 4
#define ODIM 64
#define ALPHA 0.2f

typedef __attribute__((ext_vector_type(8))) short bf16x8;
typedef __attribute__((ext_vector_type(4))) float f32x4;

__device__ __forceinline__ ushort f2bf(float f) {
    unsigned u = __float_as_uint(f);
    unsigned r = (u + 0x7fffu + ((u >> 16) & 1u)) >> 16;   // RTNE
    return (ushort)r;
}
__device__ __forceinline__ float bf2f(ushort h) {
    return __uint_as_float(((unsigned)h) << 16);
}

// ---------------- repack weights -> bf16 hi/lo, transposed to [n][k] ----------------
// mat0: Bt[c][k] = W0[c>>6][k][c&63]; mat1: same from W1; mat2: Bt[c][k] = linW[c][k]
__global__ __launch_bounds__(256) void repack_kernel(
    const float* __restrict__ W0, const float* __restrict__ W1,
    const float* __restrict__ linW,
    ushort* __restrict__ Wth, ushort* __restrict__ Wtl)
{
    int g = blockIdx.x * 256 + threadIdx.x;   // 0 .. 3*65536-1
    int mat = g >> 16;
    int idx = g & 65535;
    int c = idx >> 8, k = idx & 255;
    float v;
    if (mat == 0)      v = W0[(c >> 6) * (256 * 64) + k * 64 + (c & 63)];
    else if (mat == 1) v = W1[(c >> 6) * (256 * 64) + k * 64 + (c & 63)];
    else               v = linW[c * 256 + k];
    ushort h = f2bf(v);
    Wth[g] = h;
    Wtl[g] = f2bf(v - bf2f(h));
}

// ---------------- fp32 -> bf16 hi/lo conversion (for input x) ----------------
__global__ __launch_bounds__(256) void conv_kernel(
    const float* __restrict__ in, ushort* __restrict__ hi, ushort* __restrict__ lo, int n4)
{
    int i = blockIdx.x * 256 + threadIdx.x;
    if (i >= n4) return;
    float4 v = ((const float4*)in)[i];
    ushort4 h, l;
    h.x = f2bf(v.x); l.x = f2bf(v.x - bf2f(h.x));
    h.y = f2bf(v.y); l.y = f2bf(v.y - bf2f(h.y));
    h.z = f2bf(v.z); l.z = f2bf(v.z - bf2f(h.z));
    h.w = f2bf(v.w); l.w = f2bf(v.w - bf2f(h.w));
    ((ushort4*)hi)[i] = h;
    ((ushort4*)lo)[i] = l;
}

// ---------------- split-bf16 MFMA GEMM: out[M x 256] = A[M x 256] * B[256 x 256] ----
// A given as hi/lo bf16 row-major [m][k]; B given as hi/lo bf16 TRANSPOSED [n][k].
// Block = 256 threads = 4 waves; wave w covers cols 64w..64w+63; wave tile RT*16 rows.
// A.hi*B.hi + A.hi*B.lo + A.lo*B.hi  (lo*lo term ~2^-18, dropped).
template<int RT, int EPI>
__global__ __launch_bounds__(256) void gemm_mfma(
    const ushort* __restrict__ Ah, const ushort* __restrict__ Al,
    const ushort* __restrict__ Bh, const ushort* __restrict__ Bl,
    const float* __restrict__ bias, float* __restrict__ out, int M)
{
    const int wave = threadIdx.x >> 6;
    const int lane = threadIdx.x & 63;
    const int quad = lane >> 4, l16 = lane & 15;
    const int row0 = blockIdx.x * (RT * 16);
    const int col0 = wave * 64;

    f32x4 acc[RT][4];
#pragma unroll
    for (int r = 0; r < RT; ++r)
#pragma unroll
        for (int c = 0; c < 4; ++c) acc[r][c] = (f32x4){0.f, 0.f, 0.f, 0.f};

    int arow[RT];
#pragma unroll
    for (int r = 0; r < RT; ++r) {
        int rr = row0 + r * 16 + l16;
        arow[r] = (rr < M) ? rr : (M - 1);   // clamp: reads stay in-bounds
    }
    const int kbase = quad * 8;

    for (int k0 = 0; k0 < 256; k0 += 32) {
        bf16x8 a_h[RT], a_l[RT], b_h[4], b_l[4];
#pragma unroll
        for (int r = 0; r < RT; ++r) {
            int off = arow[r] * 256 + k0 + kbase;
            a_h[r] = *(const bf16x8*)(Ah + off);
            a_l[r] = *(const bf16x8*)(Al + off);
        }
#pragma unroll
        for (int c = 0; c < 4; ++c) {
            int off = (col0 + c * 16 + l16) * 256 + k0 + kbase;
            b_h[c] = *(const bf16x8*)(Bh + off);
            b_l[c] = *(const bf16x8*)(Bl + off);
        }
#pragma unroll
        for (int r = 0; r < RT; ++r)
#pragma unroll
            for (int c = 0; c < 4; ++c) {
                acc[r][c] = __builtin_amdgcn_mfma_f32_16x16x32_bf16(a_h[r], b_h[c], acc[r][c], 0, 0, 0);
                acc[r][c] = __builtin_amdgcn_mfma_f32_16x16x32_bf16(a_h[r], b_l[c], acc[r][c], 0, 0, 0);
                acc[r][c] = __builtin_amdgcn_mfma_f32_16x16x32_bf16(a_l[r], b_h[c], acc[r][c], 0, 0, 0);
            }
    }

    // C/D layout: col = lane&15, row = quad*4 + reg  [measured m89/m91]
#pragma unroll
    for (int r = 0; r < RT; ++r)
#pragma unroll
        for (int c = 0; c < 4; ++c) {
            int col = col0 + c * 16 + l16;
#pragma unroll
            for (int reg = 0; reg < 4; ++reg) {
                int row = row0 + r * 16 + quad * 4 + reg;
                if (row < M) {
                    float v = acc[r][c][reg];
                    if (EPI == 1) v = tanhf(v + bias[col]);
                    out[row * 256 + col] = v;
                }
            }
        }
}

// ---------------- per-node attention scores ----------------
__global__ __launch_bounds__(64) void scores_kernel(
    const float* __restrict__ h, const float* __restrict__ a,
    float* __restrict__ s_t, float* __restrict__ s_n, int N)
{
    const int n = blockIdx.x;
    const int lane = threadIdx.x;
#pragma unroll
    for (int hd = 0; hd < NHEAD; ++hd) {
        float v = h[n * CH + hd * ODIM + lane];
        float pt = v * a[hd * 2 * ODIM + lane];
        float pn = v * a[hd * 2 * ODIM + ODIM + lane];
#pragma unroll
        for (int off = 32; off > 0; off >>= 1) {
            pt += __shfl_down(pt, off);
            pn += __shfl_down(pn, off);
        }
        if (lane == 0) { s_t[hd * N + n] = pt; s_n[hd * N + n] = pn; }
    }
}

// ---------------- per-target: dedupe, edge-softmax, aggregate, ELU; emit bf16 hi/lo --
__global__ __launch_bounds__(256) void att_kernel(
    const float* __restrict__ hprev, const int* __restrict__ nbr_arr,
    const float* __restrict__ s_t, const float* __restrict__ s_n,
    ushort* __restrict__ outhi, ushort* __restrict__ outlo, int T, int Nsrc)
{
    __shared__ int nbr[DEG + 1];
    __shared__ int keep[DEG + 1];
    __shared__ float ev[NHEAD][DEG + 1];
    __shared__ float att[NHEAD][DEG + 1];
    const int tgt = blockIdx.x;
    const int t = threadIdx.x;
    if (t < DEG) nbr[t] = nbr_arr[tgt * DEG + t];
    else if (t == DEG) nbr[DEG] = nbr_arr[T * DEG + tgt];  // self-loop
    __syncthreads();
    if (t < DEG + 1) {
        int me = nbr[t]; int k = 1;
        for (int j = 0; j < t; ++j) if (nbr[j] == me) { k = 0; break; }
        keep[t] = k;
    }
    if (t < NHEAD * (DEG + 1)) {
        int hd = t / (DEG + 1), i = t % (DEG + 1);
        float e = s_t[hd * Nsrc + tgt] + s_n[hd * Nsrc + nbr[i]];
        ev[hd][i] = (e >= 0.f) ? e : ALPHA * e;   // LeakyReLU(0.2)
    }
    __syncthreads();
    if (t < NHEAD) {
        float m = -1e30f;
        for (int i = 0; i <= DEG; ++i) if (keep[i]) m = fmaxf(m, ev[t][i]);
        float Z = 0.f;
        for (int i = 0; i <= DEG; ++i) {
            float w = keep[i] ? expf(ev[t][i] - m) : 0.f;
            Z += w; att[t][i] = w;
        }
        float rz = 1.f / Z;
        for (int i = 0; i <= DEG; ++i) att[t][i] *= rz;
    }
    __syncthreads();
    const int hd = t >> 6;
    float acc = 0.f;
    for (int i = 0; i <= DEG; ++i) {
        float w = att[hd][i];                    // wave-uniform
        if (w > 0.f) acc += w * hprev[nbr[i] * CH + t];
    }
    float v = (acc > 0.f) ? acc : expm1f(acc);   // ELU
    ushort h = f2bf(v);
    outhi[tgt * CH + t] = h;
    outlo[tgt * CH + t] = f2bf(v - bf2f(h));
}

extern "C" void kernel_launch(void* const* d_in, const int* in_sizes, int n_in,
                              void* d_out, int out_size, void* d_ws, size_t ws_size,
                              hipStream_t stream)
{
    const float* x    = (const float*)d_in[0];
    const float* W0   = (const float*)d_in[1];
    const float* a0   = (const float*)d_in[2];
    const float* W1   = (const float*)d_in[3];
    const float* a1   = (const float*)d_in[4];
    const float* linW = (const float*)d_in[5];
    const float* linb = (const float*)d_in[6];
    const int* adj1_nbr = (const int*)d_in[8];
    const int* adj0_nbr = (const int*)d_in[10];

    char* base = (char*)d_ws;
    ushort* Wth = (ushort*)base;                       // 3*65536 ushort = 384 KB
    ushort* Wtl = Wth + 3 * 65536;                     // 384 KB
    float*  st  = (float*)(base + 786432);             // 64000 f32 (256 KB slot)
    float*  sn  = st + 65536;                          // 64000 f32
    float*  h0  = (float*)(base + 1310720);            // 16000*256 f32 = 16.384 MB (reused as h1)
    ushort* xhi = (ushort*)(base + 1310720 + 16384000);// 16000*256 us = 8.192 MB
    ushort* xlo = xhi + 4096000;                       // 8.192 MB
    // x1 / x2 hi-lo pairs reuse the xhi/xlo regions (x dead after GEMM1)
    ushort* x1hi = xhi, *x1lo = xlo;
    ushort* x2hi = xhi, *x2lo = xlo;

    repack_kernel<<<768, 256, 0, stream>>>(W0, W1, linW, Wth, Wtl);
    conv_kernel<<<(N2C * 64 + 255) / 256, 256, 0, stream>>>(x, xhi, xlo, N2C * 64);

    // layer 1: h0 = x @ Wc0
    gemm_mfma<2, 0><<<N2C / 32, 256, 0, stream>>>(xhi, xlo, Wth, Wtl, nullptr, h0, N2C);
    scores_kernel<<<N2C, 64, 0, stream>>>(h0, a0, st, sn, N2C);
    att_kernel<<<N1C, 256, 0, stream>>>(h0, adj1_nbr, st, sn, x1hi, x1lo, N1C, N2C);

    // layer 2: h1 = x1 @ Wc1 (h1 aliases h0)
    gemm_mfma<1, 0><<<N1C / 16, 256, 0, stream>>>(x1hi, x1lo, Wth + 65536, Wtl + 65536, nullptr, h0, N1C);
    scores_kernel<<<N1C, 64, 0, stream>>>(h0, a1, st, sn, N1C);
    att_kernel<<<N0C, 256, 0, stream>>>(h0, adj0_nbr, st, sn, x2hi, x2lo, N0C, N1C);

    // final Linear + Tanh: out = tanh(x2 @ linW^T + b)
    gemm_mfma<1, 1><<<(N0C + 15) / 16, 256, 0, stream>>>(x2hi, x2lo, Wth + 131072, Wtl + 131072, linb, (float*)d_out, N0C);
}

// Round 3
// 193.964 us; speedup vs baseline: 1.7771x; 1.2498x over previous
//
#include <hip/hip_runtime.h>
#include <math.h>

#define N2C 16000
#define N1C 4000
#define N0C 1000
#define DEG 32
#define CH 256      // H*O
#define NHEAD 4
#define ODIM 64
#define ALPHA 0.2f

typedef __attribute__((ext_vector_type(8))) short bf16x8;
typedef __attribute__((ext_vector_type(4))) float f32x4;

__device__ __forceinline__ ushort f2bf(float f) {
    unsigned u = __float_as_uint(f);
    unsigned r = (u + 0x7fffu + ((u >> 16) & 1u)) >> 16;   // RTNE
    return (ushort)r;
}
__device__ __forceinline__ float bf2f(ushort h) {
    return __uint_as_float(((unsigned)h) << 16);
}

// ---------------- repack weights -> bf16 hi/lo, transposed to [n][k] ----------------
__global__ __launch_bounds__(256) void repack_kernel(
    const float* __restrict__ W0, const float* __restrict__ W1,
    const float* __restrict__ linW,
    ushort* __restrict__ Wth, ushort* __restrict__ Wtl)
{
    int g = blockIdx.x * 256 + threadIdx.x;   // 0 .. 3*65536-1
    int mat = g >> 16;
    int idx = g & 65535;
    int c = idx >> 8, k = idx & 255;
    float v;
    if (mat == 0)      v = W0[(c >> 6) * (256 * 64) + k * 64 + (c & 63)];
    else if (mat == 1) v = W1[(c >> 6) * (256 * 64) + k * 64 + (c & 63)];
    else               v = linW[c * 256 + k];
    ushort h = f2bf(v);
    Wth[g] = h;
    Wtl[g] = f2bf(v - bf2f(h));
}

// ---------------- split-bf16 MFMA GEMM + fused score epilogue -----------------------
// out[M x 256] = A[M x 256] * B[256 x 256];  B as hi/lo bf16 transposed [n][k].
// AF32=1: A is fp32 row-major, converted to hi/lo in-register.
// SC=1: also emit s_t/s_n (per-head dots with avec) — wave w holds head w's 64 cols.
template<int RT, int EPI, int AF32, int SC>
__global__ __launch_bounds__(256) void gemm_mfma(
    const float* __restrict__ Af,
    const ushort* __restrict__ Ah, const ushort* __restrict__ Al,
    const ushort* __restrict__ Bh, const ushort* __restrict__ Bl,
    const float* __restrict__ bias, const float* __restrict__ avec,
    float* __restrict__ out, float* __restrict__ s_t, float* __restrict__ s_n, int M)
{
    const int wave = threadIdx.x >> 6;
    const int lane = threadIdx.x & 63;
    const int quad = lane >> 4, l16 = lane & 15;
    const int row0 = blockIdx.x * (RT * 16);
    const int col0 = wave * 64;

    f32x4 acc[RT][4];
#pragma unroll
    for (int r = 0; r < RT; ++r)
#pragma unroll
        for (int c = 0; c < 4; ++c) acc[r][c] = (f32x4){0.f, 0.f, 0.f, 0.f};

    int arow[RT];
#pragma unroll
    for (int r = 0; r < RT; ++r) {
        int rr = row0 + r * 16 + l16;
        arow[r] = (rr < M) ? rr : (M - 1);   // clamp: reads stay in-bounds
    }
    const int kbase = quad * 8;

    for (int k0 = 0; k0 < 256; k0 += 32) {
        bf16x8 a_h[RT], a_l[RT], b_h[4], b_l[4];
#pragma unroll
        for (int r = 0; r < RT; ++r) {
            int off = arow[r] * 256 + k0 + kbase;
            if (AF32) {
                float4 f0 = *(const float4*)(Af + off);
                float4 f1 = *(const float4*)(Af + off + 4);
                float fv[8] = {f0.x, f0.y, f0.z, f0.w, f1.x, f1.y, f1.z, f1.w};
#pragma unroll
                for (int e = 0; e < 8; ++e) {
                    ushort hh = f2bf(fv[e]);
                    a_h[r][e] = (short)hh;
                    a_l[r][e] = (short)f2bf(fv[e] - bf2f(hh));
                }
            } else {
                a_h[r] = *(const bf16x8*)(Ah + off);
                a_l[r] = *(const bf16x8*)(Al + off);
            }
        }
#pragma unroll
        for (int c = 0; c < 4; ++c) {
            int off = (col0 + c * 16 + l16) * 256 + k0 + kbase;
            b_h[c] = *(const bf16x8*)(Bh + off);
            b_l[c] = *(const bf16x8*)(Bl + off);
        }
#pragma unroll
        for (int r = 0; r < RT; ++r)
#pragma unroll
            for (int c = 0; c < 4; ++c) {
                acc[r][c] = __builtin_amdgcn_mfma_f32_16x16x32_bf16(a_h[r], b_h[c], acc[r][c], 0, 0, 0);
                acc[r][c] = __builtin_amdgcn_mfma_f32_16x16x32_bf16(a_h[r], b_l[c], acc[r][c], 0, 0, 0);
                acc[r][c] = __builtin_amdgcn_mfma_f32_16x16x32_bf16(a_l[r], b_h[c], acc[r][c], 0, 0, 0);
            }
    }

    // C/D layout: col = lane&15, row = quad*4 + reg  [measured m89/m91]
#pragma unroll
    for (int r = 0; r < RT; ++r)
#pragma unroll
        for (int c = 0; c < 4; ++c) {
            int col = col0 + c * 16 + l16;
#pragma unroll
            for (int reg = 0; reg < 4; ++reg) {
                int row = row0 + r * 16 + quad * 4 + reg;
                if (row < M) {
                    float v = acc[r][c][reg];
                    if (EPI == 1) v = tanhf(v + bias[col]);
                    out[row * 256 + col] = v;
                }
            }
        }

    if (SC) {
        // head hd == wave; per-lane channels: c*16+l16, c=0..3
        float at[4], an[4];
#pragma unroll
        for (int c = 0; c < 4; ++c) {
            at[c] = avec[wave * 128 + c * 16 + l16];
            an[c] = avec[wave * 128 + 64 + c * 16 + l16];
        }
#pragma unroll
        for (int r = 0; r < RT; ++r) {
            float pt[4] = {0.f, 0.f, 0.f, 0.f}, pn[4] = {0.f, 0.f, 0.f, 0.f};
#pragma unroll
            for (int c = 0; c < 4; ++c)
#pragma unroll
                for (int reg = 0; reg < 4; ++reg) {
                    pt[reg] += acc[r][c][reg] * at[c];
                    pn[reg] += acc[r][c][reg] * an[c];
                }
#pragma unroll
            for (int reg = 0; reg < 4; ++reg)
#pragma unroll
                for (int m = 1; m < 16; m <<= 1) {
                    pt[reg] += __shfl_xor(pt[reg], m);
                    pn[reg] += __shfl_xor(pn[reg], m);
                }
            if (l16 == 0) {
#pragma unroll
                for (int reg = 0; reg < 4; ++reg) {
                    int row = row0 + r * 16 + quad * 4 + reg;
                    if (row < M) {
                        s_t[wave * M + row] = pt[reg];
                        s_n[wave * M + row] = pn[reg];
                    }
                }
            }
        }
    }
}

// ---------------- per-target: dedupe, edge-softmax, float4 aggregate, ELU -----------
__global__ __launch_bounds__(256) void att_kernel(
    const float* __restrict__ hprev, const int* __restrict__ nbr_arr,
    const float* __restrict__ s_t, const float* __restrict__ s_n,
    ushort* __restrict__ outhi, ushort* __restrict__ outlo, int T, int Nsrc)
{
    __shared__ int nbr[DEG + 1];
    __shared__ int keep[DEG + 1];
    __shared__ float ev[NHEAD][DEG + 1];
    __shared__ float att_s[NHEAD][DEG + 1];
    __shared__ float4 red[4][64];
    const int tgt = blockIdx.x;
    const int t = threadIdx.x;
    if (t < DEG) nbr[t] = nbr_arr[tgt * DEG + t];
    else if (t == DEG) nbr[DEG] = nbr_arr[T * DEG + tgt];  // self-loop edge
    __syncthreads();
    if (t < DEG + 1) {
        int me = nbr[t]; int k = 1;
        for (int j = 0; j < t; ++j) if (nbr[j] == me) { k = 0; break; }
        keep[t] = k;
    }
    if (t < NHEAD * (DEG + 1)) {
        int hd = t / (DEG + 1), i = t % (DEG + 1);
        float e = s_t[hd * Nsrc + tgt] + s_n[hd * Nsrc + nbr[i]];
        ev[hd][i] = (e >= 0.f) ? e : ALPHA * e;   // LeakyReLU(0.2)
    }
    __syncthreads();
    if (t < NHEAD) {
        float m = -1e30f;
        for (int i = 0; i <= DEG; ++i) if (keep[i]) m = fmaxf(m, ev[t][i]);
        float Z = 0.f;
        for (int i = 0; i <= DEG; ++i) {
            float w = keep[i] ? expf(ev[t][i] - m) : 0.f;
            Z += w; att_s[t][i] = w;
        }
        float rz = 1.f / Z;
        for (int i = 0; i <= DEG; ++i) att_s[t][i] *= rz;
    }
    __syncthreads();
    // aggregation: thread = (rg = t>>6 row-group, cq = t&63 channel-quad)
    const int cq = t & 63;
    const int rg = t >> 6;
    const int hd = cq >> 4;
    const float4* hp4 = (const float4*)hprev;
    float4 acc = make_float4(0.f, 0.f, 0.f, 0.f);
#pragma unroll
    for (int ii = 0; ii < 9; ++ii) {
        int i = rg + ii * 4;
        if (i <= DEG) {
            float w = att_s[hd][i];                       // dup edges: w==0
            float4 v = hp4[(size_t)nbr[i] * 64 + cq];
            acc.x += w * v.x; acc.y += w * v.y;
            acc.z += w * v.z; acc.w += w * v.w;
        }
    }
    red[rg][cq] = acc;
    __syncthreads();
    if (t < 64) {
        float4 s0 = red[0][t], s1 = red[1][t], s2 = red[2][t], s3 = red[3][t];
        float4 s;
        s.x = s0.x + s1.x + s2.x + s3.x;
        s.y = s0.y + s1.y + s2.y + s3.y;
        s.z = s0.z + s1.z + s2.z + s3.z;
        s.w = s0.w + s1.w + s2.w + s3.w;
        s.x = (s.x > 0.f) ? s.x : expm1f(s.x);   // ELU
        s.y = (s.y > 0.f) ? s.y : expm1f(s.y);
        s.z = (s.z > 0.f) ? s.z : expm1f(s.z);
        s.w = (s.w > 0.f) ? s.w : expm1f(s.w);
        ushort4 h, l;
        h.x = f2bf(s.x); l.x = f2bf(s.x - bf2f(h.x));
        h.y = f2bf(s.y); l.y = f2bf(s.y - bf2f(h.y));
        h.z = f2bf(s.z); l.z = f2bf(s.z - bf2f(h.z));
        h.w = f2bf(s.w); l.w = f2bf(s.w - bf2f(h.w));
        ((ushort4*)outhi)[tgt * 64 + t] = h;
        ((ushort4*)outlo)[tgt * 64 + t] = l;
    }
}

extern "C" void kernel_launch(void* const* d_in, const int* in_sizes, int n_in,
                              void* d_out, int out_size, void* d_ws, size_t ws_size,
                              hipStream_t stream)
{
    const float* x    = (const float*)d_in[0];
    const float* W0   = (const float*)d_in[1];
    const float* a0   = (const float*)d_in[2];
    const float* W1   = (const float*)d_in[3];
    const float* a1   = (const float*)d_in[4];
    const float* linW = (const float*)d_in[5];
    const float* linb = (const float*)d_in[6];
    const int* adj1_nbr = (const int*)d_in[8];
    const int* adj0_nbr = (const int*)d_in[10];

    char* base = (char*)d_ws;
    ushort* Wth = (ushort*)base;                       // 3*65536 ushort = 384 KB
    ushort* Wtl = Wth + 3 * 65536;                     // 384 KB
    float*  st  = (float*)(base + 786432);             // 4*16000 f32
    float*  sn  = st + 65536;
    float*  h0  = (float*)(base + 1310720);            // 16000*256 f32 (reused as h1)
    ushort* xhi = (ushort*)(base + 1310720 + 16384000);// att outputs (bf16 hi/lo)
    ushort* xlo = xhi + 4096000;

    repack_kernel<<<768, 256, 0, stream>>>(W0, W1, linW, Wth, Wtl);

    // layer 1: h0 = x @ Wc0 (fp32 A converted in-register) + fused scores
    gemm_mfma<2, 0, 1, 1><<<N2C / 32, 256, 0, stream>>>(
        x, nullptr, nullptr, Wth, Wtl, nullptr, a0, h0, st, sn, N2C);
    att_kernel<<<N1C, 256, 0, stream>>>(h0, adj1_nbr, st, sn, xhi, xlo, N1C, N2C);

    // layer 2: h1 = x1 @ Wc1 (h1 aliases h0) + fused scores
    gemm_mfma<1, 0, 0, 1><<<N1C / 16, 256, 0, stream>>>(
        nullptr, xhi, xlo, Wth + 65536, Wtl + 65536, nullptr, a1, h0, st, sn, N1C);
    att_kernel<<<N0C, 256, 0, stream>>>(h0, adj0_nbr, st, sn, xhi, xlo, N0C, N1C);

    // final Linear + Tanh
    gemm_mfma<1, 1, 0, 0><<<(N0C + 15) / 16, 256, 0, stream>>>(
        nullptr, xhi, xlo, Wth + 131072, Wtl + 131072, linb, nullptr,
        (float*)d_out, nullptr, nullptr, N0C);
}

// Round 4
// 166.793 us; speedup vs baseline: 2.0666x; 1.1629x over previous
//
#include <hip/hip_runtime.h>
#include <math.h>

#define N2C 16000
#define N1C 4000
#define N0C 1000
#define DEG 32
#define CH 256      // H*O
#define NHEAD 4
#define ODIM 64
#define ALPHA 0.2f
#define LDP 264     // padded LDS row pitch (ushorts): 264*2=528 B, 16B-aligned, 2-way banks

typedef __attribute__((ext_vector_type(8))) short bf16x8;
typedef __attribute__((ext_vector_type(4))) float f32x4;

__device__ __forceinline__ ushort f2bf(float f) {
    unsigned u = __float_as_uint(f);
    unsigned r = (u + 0x7fffu + ((u >> 16) & 1u)) >> 16;   // RTNE
    return (ushort)r;
}
__device__ __forceinline__ float bf2f(ushort h) {
    return __uint_as_float(((unsigned)h) << 16);
}

// ---------------- repack weights -> bf16 hi/lo, transposed to [n][k] ----------------
__global__ __launch_bounds__(256) void repack_kernel(
    const float* __restrict__ W0, const float* __restrict__ W1,
    const float* __restrict__ linW,
    ushort* __restrict__ Wth, ushort* __restrict__ Wtl)
{
    int g = blockIdx.x * 256 + threadIdx.x;   // 0 .. 3*65536-1
    int mat = g >> 16;
    int idx = g & 65535;
    int c = idx >> 8, k = idx & 255;
    float v;
    if (mat == 0)      v = W0[(c >> 6) * (256 * 64) + k * 64 + (c & 63)];
    else if (mat == 1) v = W1[(c >> 6) * (256 * 64) + k * 64 + (c & 63)];
    else               v = linW[c * 256 + k];
    ushort h = f2bf(v);
    Wth[g] = h;
    Wtl[g] = f2bf(v - bf2f(h));
}

// ---------------- split-bf16 MFMA GEMM + fused score epilogue -----------------------
// out[M x 256] = A[M x 256] * B[256 x 256];  B as hi/lo bf16 transposed [n][k].
// AF32=1: A fp32 row-major, converted ONCE per block into LDS hi/lo (shared by 4 waves).
// SC=1: also emit s_t/s_n (per-head dots with avec) — wave w holds head w's 64 cols.
template<int RT, int EPI, int AF32, int SC>
__global__ __launch_bounds__(256) void gemm_mfma(
    const float* __restrict__ Af,
    const ushort* __restrict__ Ah, const ushort* __restrict__ Al,
    const ushort* __restrict__ Bh, const ushort* __restrict__ Bl,
    const float* __restrict__ bias, const float* __restrict__ avec,
    float* __restrict__ out, float* __restrict__ s_t, float* __restrict__ s_n, int M)
{
    __shared__ ushort sah[AF32 ? RT * 16 * LDP : 1];
    __shared__ ushort sal[AF32 ? RT * 16 * LDP : 1];

    const int wave = threadIdx.x >> 6;
    const int lane = threadIdx.x & 63;
    const int quad = lane >> 4, l16 = lane & 15;
    const int row0 = blockIdx.x * (RT * 16);
    const int col0 = wave * 64;

    if (AF32) {
        // cooperative stage: fp32 A tile -> hi/lo bf16 in LDS (once per block)
        for (int idx = threadIdx.x; idx < RT * 16 * 64; idx += 256) {
            int row = idx >> 6, c4 = idx & 63;
            int gr = row0 + row; if (gr >= M) gr = M - 1;
            float4 f = ((const float4*)Af)[gr * 64 + c4];
            ushort4 h, l;
            h.x = f2bf(f.x); l.x = f2bf(f.x - bf2f(h.x));
            h.y = f2bf(f.y); l.y = f2bf(f.y - bf2f(h.y));
            h.z = f2bf(f.z); l.z = f2bf(f.z - bf2f(h.z));
            h.w = f2bf(f.w); l.w = f2bf(f.w - bf2f(h.w));
            *(ushort4*)(&sah[row * LDP + c4 * 4]) = h;
            *(ushort4*)(&sal[row * LDP + c4 * 4]) = l;
        }
        __syncthreads();
    }

    f32x4 acc[RT][4];
#pragma unroll
    for (int r = 0; r < RT; ++r)
#pragma unroll
        for (int c = 0; c < 4; ++c) acc[r][c] = (f32x4){0.f, 0.f, 0.f, 0.f};

    int arow[RT];
#pragma unroll
    for (int r = 0; r < RT; ++r) {
        int rr = row0 + r * 16 + l16;
        arow[r] = (rr < M) ? rr : (M - 1);   // clamp: reads stay in-bounds
    }
    const int kbase = quad * 8;

    for (int k0 = 0; k0 < 256; k0 += 32) {
        bf16x8 a_h[RT], a_l[RT], b_h[4], b_l[4];
#pragma unroll
        for (int r = 0; r < RT; ++r) {
            if (AF32) {
                int loff = (r * 16 + l16) * LDP + k0 + kbase;
                a_h[r] = *(const bf16x8*)(&sah[loff]);   // ds_read_b128, 2-way banks
                a_l[r] = *(const bf16x8*)(&sal[loff]);
            } else {
                int off = arow[r] * 256 + k0 + kbase;
                a_h[r] = *(const bf16x8*)(Ah + off);
                a_l[r] = *(const bf16x8*)(Al + off);
            }
        }
#pragma unroll
        for (int c = 0; c < 4; ++c) {
            int off = (col0 + c * 16 + l16) * 256 + k0 + kbase;
            b_h[c] = *(const bf16x8*)(Bh + off);
            b_l[c] = *(const bf16x8*)(Bl + off);
        }
#pragma unroll
        for (int r = 0; r < RT; ++r)
#pragma unroll
            for (int c = 0; c < 4; ++c) {
                acc[r][c] = __builtin_amdgcn_mfma_f32_16x16x32_bf16(a_h[r], b_h[c], acc[r][c], 0, 0, 0);
                acc[r][c] = __builtin_amdgcn_mfma_f32_16x16x32_bf16(a_h[r], b_l[c], acc[r][c], 0, 0, 0);
                acc[r][c] = __builtin_amdgcn_mfma_f32_16x16x32_bf16(a_l[r], b_h[c], acc[r][c], 0, 0, 0);
            }
    }

    // C/D layout: col = lane&15, row = quad*4 + reg  [measured m89/m91]
#pragma unroll
    for (int r = 0; r < RT; ++r)
#pragma unroll
        for (int c = 0; c < 4; ++c) {
            int col = col0 + c * 16 + l16;
#pragma unroll
            for (int reg = 0; reg < 4; ++reg) {
                int row = row0 + r * 16 + quad * 4 + reg;
                if (row < M) {
                    float v = acc[r][c][reg];
                    if (EPI == 1) v = tanhf(v + bias[col]);
                    out[row * 256 + col] = v;
                }
            }
        }

    if (SC) {
        // head hd == wave; per-lane channels: c*16+l16, c=0..3
        float at[4], an[4];
#pragma unroll
        for (int c = 0; c < 4; ++c) {
            at[c] = avec[wave * 128 + c * 16 + l16];
            an[c] = avec[wave * 128 + 64 + c * 16 + l16];
        }
#pragma unroll
        for (int r = 0; r < RT; ++r) {
            float pt[4] = {0.f, 0.f, 0.f, 0.f}, pn[4] = {0.f, 0.f, 0.f, 0.f};
#pragma unroll
            for (int c = 0; c < 4; ++c)
#pragma unroll
                for (int reg = 0; reg < 4; ++reg) {
                    pt[reg] += acc[r][c][reg] * at[c];
                    pn[reg] += acc[r][c][reg] * an[c];
                }
#pragma unroll
            for (int reg = 0; reg < 4; ++reg)
#pragma unroll
                for (int m = 1; m < 16; m <<= 1) {
                    pt[reg] += __shfl_xor(pt[reg], m);
                    pn[reg] += __shfl_xor(pn[reg], m);
                }
            if (l16 == 0) {
#pragma unroll
                for (int reg = 0; reg < 4; ++reg) {
                    int row = row0 + r * 16 + quad * 4 + reg;
                    if (row < M) {
                        s_t[wave * M + row] = pt[reg];
                        s_n[wave * M + row] = pn[reg];
                    }
                }
            }
        }
    }
}

// ---------------- per-target: wave-parallel dedupe+softmax, float4 aggregate, ELU ---
__global__ __launch_bounds__(256) void att_kernel(
    const float* __restrict__ hprev, const int* __restrict__ nbr_arr,
    const float* __restrict__ s_t, const float* __restrict__ s_n,
    ushort* __restrict__ outhi, ushort* __restrict__ outlo, int T, int Nsrc)
{
    __shared__ int nbr[DEG + 1];
    __shared__ float att_s[NHEAD][DEG + 3];
    __shared__ float4 red[4][64];
    const int tgt = blockIdx.x;
    const int t = threadIdx.x;
    const int lane = t & 63;
    if (t < DEG) nbr[t] = nbr_arr[tgt * DEG + t];
    else if (t == DEG) nbr[DEG] = nbr_arr[T * DEG + tgt];  // self-loop edge
    __syncthreads();

    {   // wave = head; lane = edge index (33 edges), lanes 33..63 inert
        const int hd = t >> 6;
        int me = (lane <= DEG) ? nbr[lane] : -1;
        int k = (lane <= DEG) ? 1 : 0;
#pragma unroll
        for (int j = 0; j < DEG; ++j) {          // dedupe scan via shuffle
            int v = __shfl(me, j);
            if (j < lane && v == me) k = 0;
        }
        float e = s_t[hd * Nsrc + tgt] + ((lane <= DEG) ? s_n[hd * Nsrc + me] : 0.f);
        e = (e >= 0.f) ? e : ALPHA * e;          // LeakyReLU(0.2)
        float em = k ? e : -1e30f;
        float m = em;
#pragma unroll
        for (int off = 1; off < 64; off <<= 1) m = fmaxf(m, __shfl_xor(m, off));
        float w = k ? __expf(e - m) : 0.f;
        float Z = w;
#pragma unroll
        for (int off = 1; off < 64; off <<= 1) Z += __shfl_xor(Z, off);
        if (lane <= DEG) att_s[hd][lane] = w / Z;
    }
    __syncthreads();

    // aggregation: thread = (rg = t>>6 row-group, cq = t&63 channel-quad)
    const int cq = t & 63;
    const int rg = t >> 6;
    const int hd = cq >> 4;
    const float4* hp4 = (const float4*)hprev;
    float4 acc = make_float4(0.f, 0.f, 0.f, 0.f);
#pragma unroll
    for (int ii = 0; ii < 9; ++ii) {
        int i = rg + ii * 4;
        if (i <= DEG) {
            float w = att_s[hd][i];                       // dup edges: w==0
            float4 v = hp4[(size_t)nbr[i] * 64 + cq];
            acc.x += w * v.x; acc.y += w * v.y;
            acc.z += w * v.z; acc.w += w * v.w;
        }
    }
    red[rg][cq] = acc;
    __syncthreads();
    if (t < 64) {
        float4 s0 = red[0][t], s1 = red[1][t], s2 = red[2][t], s3 = red[3][t];
        float4 s;
        s.x = s0.x + s1.x + s2.x + s3.x;
        s.y = s0.y + s1.y + s2.y + s3.y;
        s.z = s0.z + s1.z + s2.z + s3.z;
        s.w = s0.w + s1.w + s2.w + s3.w;
        s.x = (s.x > 0.f) ? s.x : expm1f(s.x);   // ELU
        s.y = (s.y > 0.f) ? s.y : expm1f(s.y);
        s.z = (s.z > 0.f) ? s.z : expm1f(s.z);
        s.w = (s.w > 0.f) ? s.w : expm1f(s.w);
        ushort4 h, l;
        h.x = f2bf(s.x); l.x = f2bf(s.x - bf2f(h.x));
        h.y = f2bf(s.y); l.y = f2bf(s.y - bf2f(h.y));
        h.z = f2bf(s.z); l.z = f2bf(s.z - bf2f(h.z));
        h.w = f2bf(s.w); l.w = f2bf(s.w - bf2f(h.w));
        ((ushort4*)outhi)[tgt * 64 + t] = h;
        ((ushort4*)outlo)[tgt * 64 + t] = l;
    }
}

extern "C" void kernel_launch(void* const* d_in, const int* in_sizes, int n_in,
                              void* d_out, int out_size, void* d_ws, size_t ws_size,
                              hipStream_t stream)
{
    const float* x    = (const float*)d_in[0];
    const float* W0   = (const float*)d_in[1];
    const float* a0   = (const float*)d_in[2];
    const float* W1   = (const float*)d_in[3];
    const float* a1   = (const float*)d_in[4];
    const float* linW = (const float*)d_in[5];
    const float* linb = (const float*)d_in[6];
    const int* adj1_nbr = (const int*)d_in[8];
    const int* adj0_nbr = (const int*)d_in[10];

    char* base = (char*)d_ws;
    ushort* Wth = (ushort*)base;                       // 3*65536 ushort = 384 KB
    ushort* Wtl = Wth + 3 * 65536;                     // 384 KB
    float*  st  = (float*)(base + 786432);             // 4*16000 f32
    float*  sn  = st + 65536;
    float*  h0  = (float*)(base + 1310720);            // 16000*256 f32 (reused as h1)
    ushort* xhi = (ushort*)(base + 1310720 + 16384000);// att outputs (bf16 hi/lo)
    ushort* xlo = xhi + 4096000;

    repack_kernel<<<768, 256, 0, stream>>>(W0, W1, linW, Wth, Wtl);

    // layer 1: h0 = x @ Wc0 (fp32 A staged+converted once per block in LDS) + scores
    gemm_mfma<2, 0, 1, 1><<<N2C / 32, 256, 0, stream>>>(
        x, nullptr, nullptr, Wth, Wtl, nullptr, a0, h0, st, sn, N2C);
    att_kernel<<<N1C, 256, 0, stream>>>(h0, adj1_nbr, st, sn, xhi, xlo, N1C, N2C);

    // layer 2: h1 = x1 @ Wc1 (h1 aliases h0) + fused scores
    gemm_mfma<1, 0, 0, 1><<<N1C / 16, 256, 0, stream>>>(
        nullptr, xhi, xlo, Wth + 65536, Wtl + 65536, nullptr, a1, h0, st, sn, N1C);
    att_kernel<<<N0C, 256, 0, stream>>>(h0, adj0_nbr, st, sn, xhi, xlo, N0C, N1C);

    // final Linear + Tanh
    gemm_mfma<1, 1, 0, 0><<<(N0C + 15) / 16, 256, 0, stream>>>(
        nullptr, xhi, xlo, Wth + 131072, Wtl + 131072, linb, nullptr,
        (float*)d_out, nullptr, nullptr, N0C);
}